// Round 9
// baseline (44678.494 us; speedup 1.0000x reference)
//
#include <hip/hip_runtime.h>
#include <hip/hip_bf16.h>
#include <math.h>

// MultiLayerRNN on gfx950 — block-autonomous recurrence (round 9).
// Round-8 lesson (PMC): VGPR=124 -> compiler sank weight "register" loads
// into the t-loop as strided scalar f32 loads => 16 ms. Fix:
//  k_prep: weights -> bf16 col-major (B-frag = one 16B vector load, L2-hot)
//  k_a:    a[t] = emb[x_t]@Wxh0 + bxh0 + bhh0 (parallel MFMA, frag layout)
//  k_main: 4 blocks x 512 thr; each block owns one 16-row batch group's
//          ENTIRE h0/h1 in LDS -> recurrence sync = __syncthreads only.
//          No atomics, no flags, no cross-block traffic. fc fused.

typedef __bf16 bf16_t;
typedef __bf16 bf16x8 __attribute__((ext_vector_type(8)));
typedef __bf16 bf16x4 __attribute__((ext_vector_type(4)));
typedef float  floatx4 __attribute__((ext_vector_type(4)));

#define S_LEN 1024
#define BATCH 64
#define EMBD  256
#define HID   512
#define VOCAB 50000
#define LDST  520   // LDS row stride (bf16): 1040B -> 2-way bank aliasing (free)

__device__ __attribute__((aligned(16))) bf16_t g_wxh0T[HID * EMBD];
__device__ __attribute__((aligned(16))) bf16_t g_whh0T[HID * HID];
__device__ __attribute__((aligned(16))) bf16_t g_wxh1T[HID * HID];
__device__ __attribute__((aligned(16))) bf16_t g_whh1T[HID * HID];
__device__ __attribute__((aligned(16))) bf16_t g_a[(size_t)S_LEN * BATCH * HID];

__device__ __forceinline__ float act_tanh(float x) {
  x = fminf(fmaxf(x, -12.0f), 12.0f);   // NaN-proof
  float e = __expf(2.0f * x);
  return 1.0f - 2.0f / (e + 1.0f);
}

// ---------- k_prep: f32 row-major W[K][512] -> bf16 col-major WT[col][K] ----
__global__ __launch_bounds__(256) void k_prep(const float* __restrict__ Wxh0,
    const float* __restrict__ Whh0, const float* __restrict__ Wxh1,
    const float* __restrict__ Whh1) {
  int idx = blockIdx.x * 256 + threadIdx.x;
  const int NA = HID * EMBD, NB = HID * HID;
  if (idx < NA) {
    int col = idx >> 8, k = idx & (EMBD - 1);
    g_wxh0T[idx] = (bf16_t)Wxh0[(size_t)k * HID + col];
  } else if (idx < NA + NB) {
    int j = idx - NA, col = j >> 9, k = j & (HID - 1);
    g_whh0T[j] = (bf16_t)Whh0[(size_t)k * HID + col];
  } else if (idx < NA + 2 * NB) {
    int j = idx - NA - NB, col = j >> 9, k = j & (HID - 1);
    g_wxh1T[j] = (bf16_t)Wxh1[(size_t)k * HID + col];
  } else if (idx < NA + 3 * NB) {
    int j = idx - NA - 2 * NB, col = j >> 9, k = j & (HID - 1);
    g_whh1T[j] = (bf16_t)Whh1[(size_t)k * HID + col];
  }
}

// ---------- k_a: a[t] = emb[x_t]@Wxh0 + bxh0 + bhh0, stored in C-frag layout
__global__ __launch_bounds__(256, 2) void k_a(const int* __restrict__ x,
    const float* __restrict__ emb, const float* __restrict__ bxh0,
    const float* __restrict__ bhh0) {
  int t = blockIdx.x;
  int tid = threadIdx.x;
  int g = tid >> 6, lane = tid & 63, l15 = lane & 15, quad = lane >> 4;
  int kb = quad * 8;
  int xi = x[(g * 16 + l15) * S_LEN + t];
  xi = xi < 0 ? 0 : (xi >= VOCAB ? VOCAB - 1 : xi);
  const float* ep = emb + (size_t)xi * EMBD + kb;
  bf16x8 ea[8];
#pragma unroll
  for (int ks = 0; ks < 8; ++ks) {
    const float* p = ep + ks * 32;
#pragma unroll
    for (int j = 0; j < 8; ++j) ea[ks][j] = (bf16_t)p[j];
  }
  for (int tile = 0; tile < 32; ++tile) {
    int col = tile * 16 + l15;
    float bb = bxh0[col] + bhh0[col];
    floatx4 acc = (floatx4){bb, bb, bb, bb};
    const bf16_t* wp = g_wxh0T + (size_t)col * EMBD + kb;
#pragma unroll
    for (int ks = 0; ks < 8; ++ks)
      acc = __builtin_amdgcn_mfma_f32_16x16x32_bf16(
          ea[ks], *(const bf16x8*)(wp + ks * 32), acc, 0, 0, 0);
    bf16x4 v;
#pragma unroll
    for (int i = 0; i < 4; ++i) v[i] = (bf16_t)acc[i];
    *(bf16x4*)(g_a + ((((size_t)t * 4 + g) * 32 + tile) << 8) + lane * 4) = v;
  }
}

// ---------- k_main: the recurrence, one block per batch-group --------------
__global__ __launch_bounds__(512, 2) void k_main(
    const float* __restrict__ bxh1, const float* __restrict__ bhh1,
    const float* __restrict__ fc_w, const float* __restrict__ fc_b,
    float* __restrict__ out) {
  __shared__ __attribute__((aligned(16))) bf16_t sh0[16 * LDST];
  __shared__ __attribute__((aligned(16))) bf16_t sh1[16 * LDST];
  int g = blockIdx.x;
  int tid = threadIdx.x;
  int w = tid >> 6, lane = tid & 63, l15 = lane & 15, quad = lane >> 4;
  int kb = quad * 8;

  // zero h-state (reference: h starts at 0)
  for (int i = tid; i < 16 * LDST; i += 512) {
    sh0[i] = (bf16_t)0.0f; sh1[i] = (bf16_t)0.0f;
  }
  // layer-1 biases for this lane's 4 tiles
  float bb1[4];
#pragma unroll
  for (int c = 0; c < 4; ++c) {
    int col = (w * 4 + c) * 16 + l15;
    bb1[c] = bxh1[col] + bhh1[col];
  }
  // prefetch a-frags for t=0
  bf16x4 af[4], afn[4];
#pragma unroll
  for (int c = 0; c < 4; ++c)
    af[c] = *(const bf16x4*)(g_a + ((((size_t)0 * 4 + g) * 32 + w * 4 + c) << 8) + lane * 4);
  __syncthreads();

  for (int t = 0; t < S_LEN; ++t) {
    // ---- phase A: h0[t] = tanh(a[t] + h0[t-1] @ Whh0) ----
    bf16x8 ah[16];
#pragma unroll
    for (int ks = 0; ks < 16; ++ks)
      ah[ks] = *(const bf16x8*)(sh0 + l15 * LDST + ks * 32 + kb);
    // prefetch next a (global, latency hidden under this step)
    if (t + 1 < S_LEN) {
#pragma unroll
      for (int c = 0; c < 4; ++c)
        afn[c] = *(const bf16x4*)(g_a + ((((size_t)(t + 1) * 4 + g) * 32 + w * 4 + c) << 8) + lane * 4);
    }
    __syncthreads();  // all waves read old h0 before overwrite
#pragma unroll
    for (int c = 0; c < 4; ++c) {
      int col = (w * 4 + c) * 16 + l15;
      floatx4 acc = (floatx4){(float)af[c][0], (float)af[c][1],
                              (float)af[c][2], (float)af[c][3]};
      const bf16_t* wp = g_whh0T + (size_t)col * HID + kb;
#pragma unroll
      for (int ks = 0; ks < 16; ++ks)
        acc = __builtin_amdgcn_mfma_f32_16x16x32_bf16(
            ah[ks], *(const bf16x8*)(wp + ks * 32), acc, 0, 0, 0);
#pragma unroll
      for (int i = 0; i < 4; ++i)
        sh0[(quad * 4 + i) * LDST + col] = (bf16_t)act_tanh(acc[i]);
    }
    __syncthreads();  // h0[t] visible

    // ---- phase B: h1[t] = tanh(h0[t]@Wxh1 + b + h1[t-1]@Whh1) ----
    bf16x8 a0[16], a1[16];
#pragma unroll
    for (int ks = 0; ks < 16; ++ks) {
      a0[ks] = *(const bf16x8*)(sh0 + l15 * LDST + ks * 32 + kb);
      a1[ks] = *(const bf16x8*)(sh1 + l15 * LDST + ks * 32 + kb);
    }
    __syncthreads();  // all waves read old h1 before overwrite
#pragma unroll
    for (int c = 0; c < 4; ++c) {
      int col = (w * 4 + c) * 16 + l15;
      floatx4 acc = (floatx4){bb1[c], bb1[c], bb1[c], bb1[c]};
      const bf16_t* wp1 = g_wxh1T + (size_t)col * HID + kb;
      const bf16_t* wp2 = g_whh1T + (size_t)col * HID + kb;
#pragma unroll
      for (int ks = 0; ks < 16; ++ks)
        acc = __builtin_amdgcn_mfma_f32_16x16x32_bf16(
            a0[ks], *(const bf16x8*)(wp1 + ks * 32), acc, 0, 0, 0);
#pragma unroll
      for (int ks = 0; ks < 16; ++ks)
        acc = __builtin_amdgcn_mfma_f32_16x16x32_bf16(
            a1[ks], *(const bf16x8*)(wp2 + ks * 32), acc, 0, 0, 0);
#pragma unroll
      for (int i = 0; i < 4; ++i)
        sh1[(quad * 4 + i) * LDST + col] = (bf16_t)act_tanh(acc[i]);
    }
    __syncthreads();  // h1[t] complete
#pragma unroll
    for (int c = 0; c < 4; ++c) af[c] = afn[c];
  }

  // ---- epilogue: out[g*16+r] = sigmoid(h1[1023] @ fc_w + fc_b) ----
  int r = tid >> 5, sub = tid & 31;
  float p = 0.0f;
#pragma unroll
  for (int j = 0; j < 16; ++j) {
    int k = sub * 16 + j;
    p += (float)sh1[r * LDST + k] * fc_w[k];
  }
#pragma unroll
  for (int o = 16; o >= 1; o >>= 1) p += __shfl_down(p, o, 32);
  if (sub == 0) {
    float acc = p + fc_b[0];
    acc = fminf(fmaxf(acc, -30.0f), 30.0f);  // NaN canary
    out[g * 16 + r] = 1.0f / (1.0f + __expf(-acc));
  }
}

extern "C" void kernel_launch(void* const* d_in, const int* in_sizes, int n_in,
                              void* d_out, int out_size, void* d_ws, size_t ws_size,
                              hipStream_t stream) {
  const int*   x    = (const int*)d_in[0];
  const float* emb  = (const float*)d_in[1];
  const float* Wxh0 = (const float*)d_in[2];
  const float* bxh0 = (const float*)d_in[3];
  const float* Whh0 = (const float*)d_in[4];
  const float* bhh0 = (const float*)d_in[5];
  const float* Wxh1 = (const float*)d_in[6];
  const float* bxh1 = (const float*)d_in[7];
  const float* Whh1 = (const float*)d_in[8];
  const float* bhh1 = (const float*)d_in[9];
  const float* fc_w = (const float*)d_in[10];
  const float* fc_b = (const float*)d_in[11];
  (void)d_ws; (void)ws_size; (void)in_sizes; (void)n_in; (void)out_size;

  const int prep_total = HID * EMBD + 3 * HID * HID;
  hipLaunchKernelGGL(k_prep, dim3((prep_total + 255) / 256), dim3(256), 0, stream,
                     Wxh0, Whh0, Wxh1, Whh1);
  hipLaunchKernelGGL(k_a, dim3(S_LEN), dim3(256), 0, stream, x, emb, bxh0, bhh0);
  hipLaunchKernelGGL(k_main, dim3(4), dim3(512), 0, stream,
                     bxh1, bhh1, fc_w, fc_b, (float*)d_out);
}

// Round 10
// 19212.233 us; speedup vs baseline: 2.3255x; 2.3255x over previous
//
#include <hip/hip_runtime.h>
#include <hip/hip_bf16.h>
#include <math.h>

// MultiLayerRNN on gfx950 — round 10: sliced dataflow + per-step weight
// re-load (pre-poll prefetch).
// r8 lesson: loop-carried weight frag arrays get sunk to scalar gathers.
// r9 lesson: 4-CU design re-streams 1.5MB/step -> L2-BW wall.
// Fix: 64 blocks (4 groups x 2 roles x 8 col-slices, 512 thr). Weights are
// bf16 col-major slices (k_prep); each step each wave re-loads its 8-16
// B-frags as b128 vector loads ISSUED BEFORE THE FLAG POLL (latency hides
// under the sync wait; no loop-carried registers). Wave-pairs split work
// (role0: K-halves, role1: matrix split), 4KB LDS reduce combines partials.
// h rings + flags use round-8's proven atomic transport.

typedef __bf16 bf16_t;
typedef __bf16 bf16x8 __attribute__((ext_vector_type(8)));
typedef __bf16 bf16x4 __attribute__((ext_vector_type(4)));
typedef float  floatx4 __attribute__((ext_vector_type(4)));
typedef unsigned int  u32;
typedef unsigned short u16;
typedef u32 u32x4 __attribute__((ext_vector_type(4)));

#define S_LEN 1024
#define BATCH 64
#define EMBD  256
#define HID   512
#define VOCAB 50000
#define D0    4
#define D1    2
#define NFLAGS (2*4*S_LEN)

__device__ __attribute__((aligned(16))) bf16_t g_wxh0T[HID * EMBD];
__device__ __attribute__((aligned(16))) bf16_t g_whh0T[HID * HID];
__device__ __attribute__((aligned(16))) bf16_t g_wxh1T[HID * HID];
__device__ __attribute__((aligned(16))) bf16_t g_whh1T[HID * HID];
__device__ __attribute__((aligned(16))) bf16_t g_a[(size_t)S_LEN * BATCH * HID];
__device__ __attribute__((aligned(16))) bf16_t g_h0[D0][BATCH * HID];
__device__ __attribute__((aligned(16))) bf16_t g_h1[D1][BATCH * HID];
__device__ int g_flags[NFLAGS];

// ---- proven cross-XCD transport: relaxed agent-scope atomics ----
__device__ __forceinline__ void at_store16(u16* p, u16 v) {
  __hip_atomic_store(p, v, __ATOMIC_RELAXED, __HIP_MEMORY_SCOPE_AGENT);
}
__device__ __forceinline__ u32 at_load32(const u32* p) {
  return __hip_atomic_load(p, __ATOMIC_RELAXED, __HIP_MEMORY_SCOPE_AGENT);
}
__device__ __forceinline__ bf16x8 at_load_frag(const bf16_t* p) {
  const u32* q = (const u32*)p;
  u32x4 w;
  w[0] = at_load32(q + 0); w[1] = at_load32(q + 1);
  w[2] = at_load32(q + 2); w[3] = at_load32(q + 3);
  return __builtin_bit_cast(bf16x8, w);
}
__device__ __forceinline__ void poll_ge(const int* p, int target) {
  while (__hip_atomic_load(p, __ATOMIC_RELAXED, __HIP_MEMORY_SCOPE_AGENT) < target)
    __builtin_amdgcn_s_sleep(2);
}

__device__ __forceinline__ float act_tanh(float x) {
  x = fminf(fmaxf(x, -12.0f), 12.0f);   // NaN-proof
  float e = __expf(2.0f * x);
  return 1.0f - 2.0f / (e + 1.0f);
}

__global__ __launch_bounds__(256) void k_init() {
  int i = blockIdx.x * 256 + threadIdx.x;
  if (i < NFLAGS)
    __hip_atomic_store(&g_flags[i], 0, __ATOMIC_RELAXED, __HIP_MEMORY_SCOPE_AGENT);
}

// ---- k_prep: f32 row-major W[K][512] -> bf16 col-major WT[col][K] ----
__global__ __launch_bounds__(256) void k_prep(const float* __restrict__ Wxh0,
    const float* __restrict__ Whh0, const float* __restrict__ Wxh1,
    const float* __restrict__ Whh1) {
  int idx = blockIdx.x * 256 + threadIdx.x;
  const int NA = HID * EMBD, NB = HID * HID;
  if (idx < NA) {
    int col = idx >> 8, k = idx & (EMBD - 1);
    g_wxh0T[idx] = (bf16_t)Wxh0[(size_t)k * HID + col];
  } else if (idx < NA + NB) {
    int j = idx - NA, col = j >> 9, k = j & (HID - 1);
    g_whh0T[j] = (bf16_t)Whh0[(size_t)k * HID + col];
  } else if (idx < NA + 2 * NB) {
    int j = idx - NA - NB, col = j >> 9, k = j & (HID - 1);
    g_wxh1T[j] = (bf16_t)Wxh1[(size_t)k * HID + col];
  } else if (idx < NA + 3 * NB) {
    int j = idx - NA - 2 * NB, col = j >> 9, k = j & (HID - 1);
    g_whh1T[j] = (bf16_t)Whh1[(size_t)k * HID + col];
  }
}

// ---- k_a: a[t] = emb[x_t]@Wxh0 + bxh0 + bhh0, in C-frag layout ----
__global__ __launch_bounds__(256, 2) void k_a(const int* __restrict__ x,
    const float* __restrict__ emb, const float* __restrict__ bxh0,
    const float* __restrict__ bhh0) {
  int t = blockIdx.x;
  int tid = threadIdx.x;
  int g = tid >> 6, lane = tid & 63, l15 = lane & 15, quad = lane >> 4;
  int kb = quad * 8;
  int xi = x[(g * 16 + l15) * S_LEN + t];
  xi = xi < 0 ? 0 : (xi >= VOCAB ? VOCAB - 1 : xi);
  const float* ep = emb + (size_t)xi * EMBD + kb;
  bf16x8 ea[8];
#pragma unroll
  for (int ks = 0; ks < 8; ++ks) {
    const float* p = ep + ks * 32;
#pragma unroll
    for (int j = 0; j < 8; ++j) ea[ks][j] = (bf16_t)p[j];
  }
  for (int tile = 0; tile < 32; ++tile) {
    int col = tile * 16 + l15;
    float bb = bxh0[col] + bhh0[col];
    floatx4 acc = (floatx4){bb, bb, bb, bb};
    const bf16_t* wp = g_wxh0T + (size_t)col * EMBD + kb;
#pragma unroll
    for (int ks = 0; ks < 8; ++ks)
      acc = __builtin_amdgcn_mfma_f32_16x16x32_bf16(
          ea[ks], *(const bf16x8*)(wp + ks * 32), acc, 0, 0, 0);
    bf16x4 v;
#pragma unroll
    for (int i = 0; i < 4; ++i) v[i] = (bf16_t)acc[i];
    *(bf16x4*)(g_a + ((((size_t)t * 4 + g) * 32 + tile) << 8) + lane * 4) = v;
  }
}

// ---- k_rnn: 64 blocks x 512 thr ----
__global__ __launch_bounds__(512, 2) void k_rnn(const float* __restrict__ bxh1,
                                                const float* __restrict__ bhh1) {
  __shared__ float red[4][64][4];   // [tile][lane][4] partial C-frags
  int* doneA = g_flags;
  int* doneB = g_flags + 4 * S_LEN;
  int bid = blockIdx.x;
  int role = bid & 1, g = (bid >> 1) & 3, s = bid >> 3;
  int tid = threadIdx.x;
  int w = tid >> 6, lane = tid & 63, l15 = lane & 15, quad = lane >> 4;
  int tile = w & 3, half = w >> 2;
  int colG = s * 64 + tile * 16 + l15;   // output column
  int arow = g * 16 + l15;               // batch row (A-frag m)
  int kb = quad * 8;

  if (role == 0) {
    // h0[t] = tanh(a[t] + h0[t-1]@Whh0); wave half h covers k in [256h,256h+256)
    const bf16_t* wbase = g_whh0T + (size_t)colG * HID + half * 256 + kb;
    for (int t = 0; t < S_LEN; ++t) {
      // pre-poll prefetch: weights (recurrence-independent; hides under wait)
      bf16x8 bw[8];
#pragma unroll
      for (int ks = 0; ks < 8; ++ks) bw[ks] = *(const bf16x8*)(wbase + ks * 32);
      floatx4 acc;
      if (half == 0) {
        bf16x4 av = *(const bf16x4*)(g_a + ((((size_t)t * 4 + g) * 32 + s * 4 + tile) << 8) + lane * 4);
        acc = (floatx4){(float)av[0], (float)av[1], (float)av[2], (float)av[3]};
      } else {
        acc = (floatx4){0.f, 0.f, 0.f, 0.f};
      }
      if (tid == 0) {
        if (t > 0)   poll_ge(&doneA[g * S_LEN + t - 1], 8);
        if (t >= D0) poll_ge(&doneB[g * S_LEN + t - D0], 8);  // ring backpressure
      }
      __syncthreads();
      if (t > 0) {
        const bf16_t* hp = g_h0[(t - 1) & (D0 - 1)] + (size_t)arow * HID + half * 256 + kb;
#pragma unroll
        for (int ks = 0; ks < 8; ++ks) {
          bf16x8 af = at_load_frag(hp + ks * 32);
          acc = __builtin_amdgcn_mfma_f32_16x16x32_bf16(af, bw[ks], acc, 0, 0, 0);
        }
      }
      if (half == 1) *(floatx4*)red[tile][lane] = acc;
      __syncthreads();
      if (half == 0) {
        floatx4 other = *(const floatx4*)red[tile][lane];
        bf16_t* hwr = g_h0[t & (D0 - 1)];
#pragma unroll
        for (int i = 0; i < 4; ++i) {
          bf16_t hv = (bf16_t)act_tanh(acc[i] + other[i]);
          at_store16((u16*)(hwr + (size_t)(g * 16 + quad * 4 + i) * HID + colG),
                     __builtin_bit_cast(u16, hv));
        }
      }
      __syncthreads();  // vmcnt(0) drain before release post; guards red reuse
      if (tid == 0)
        __hip_atomic_fetch_add(&doneA[g * S_LEN + t], 1, __ATOMIC_RELEASE,
                               __HIP_MEMORY_SCOPE_AGENT);
    }
  } else {
    // h1[t] = tanh(h0[t]@Wxh1 + b + h1[t-1]@Whh1)
    // half 0: Wxh1 (A = h0[t]);  half 1: Whh1 (A = h1[t-1])
    const bf16_t* wbase = (half ? g_whh1T : g_wxh1T) + (size_t)colG * HID + kb;
    float bb = (half == 0) ? (bxh1[colG] + bhh1[colG]) : 0.0f;
    for (int t = 0; t < S_LEN; ++t) {
      bf16x8 bw[16];
#pragma unroll
      for (int ks = 0; ks < 16; ++ks) bw[ks] = *(const bf16x8*)(wbase + ks * 32);
      if (tid == 0) {
        poll_ge(&doneA[g * S_LEN + t], 8);
        if (t > 0) poll_ge(&doneB[g * S_LEN + t - 1], 8);
      }
      __syncthreads();
      floatx4 acc = (floatx4){bb, bb, bb, bb};
      if (half == 0) {
        const bf16_t* hp = g_h0[t & (D0 - 1)] + (size_t)arow * HID + kb;
#pragma unroll
        for (int ks = 0; ks < 16; ++ks) {
          bf16x8 af = at_load_frag(hp + ks * 32);
          acc = __builtin_amdgcn_mfma_f32_16x16x32_bf16(af, bw[ks], acc, 0, 0, 0);
        }
      } else if (t > 0) {
        const bf16_t* hp = g_h1[(t - 1) & (D1 - 1)] + (size_t)arow * HID + kb;
#pragma unroll
        for (int ks = 0; ks < 16; ++ks) {
          bf16x8 af = at_load_frag(hp + ks * 32);
          acc = __builtin_amdgcn_mfma_f32_16x16x32_bf16(af, bw[ks], acc, 0, 0, 0);
        }
      }
      if (half == 1) *(floatx4*)red[tile][lane] = acc;
      __syncthreads();
      if (half == 0) {
        floatx4 other = *(const floatx4*)red[tile][lane];
        bf16_t* hwr = g_h1[t & (D1 - 1)];
#pragma unroll
        for (int i = 0; i < 4; ++i) {
          bf16_t hv = (bf16_t)act_tanh(acc[i] + other[i]);
          at_store16((u16*)(hwr + (size_t)(g * 16 + quad * 4 + i) * HID + colG),
                     __builtin_bit_cast(u16, hv));
        }
      }
      __syncthreads();
      if (tid == 0)
        __hip_atomic_fetch_add(&doneB[g * S_LEN + t], 1, __ATOMIC_RELEASE,
                               __HIP_MEMORY_SCOPE_AGENT);
    }
  }
}

// ---- k_out: out = sigmoid(h1[1023]@fc_w + fc_b) ----
__global__ __launch_bounds__(64) void k_out(const float* __restrict__ fc_w,
                                            const float* __restrict__ fc_b,
                                            float* __restrict__ out) {
  int b = threadIdx.x;
  const bf16_t* hr = g_h1[(S_LEN - 1) & (D1 - 1)] + (size_t)b * HID;
  float acc = fc_b[0];
#pragma unroll 4
  for (int k = 0; k < HID; k += 2) {
    u32 wv = at_load32((const u32*)(hr + k));
    bf16_t h0 = __builtin_bit_cast(bf16_t, (u16)(wv & 0xffffu));
    bf16_t h1 = __builtin_bit_cast(bf16_t, (u16)(wv >> 16));
    acc += (float)h0 * fc_w[k] + (float)h1 * fc_w[k + 1];
  }
  acc = fminf(fmaxf(acc, -30.0f), 30.0f);  // NaN canary
  out[b] = 1.0f / (1.0f + __expf(-acc));
}

extern "C" void kernel_launch(void* const* d_in, const int* in_sizes, int n_in,
                              void* d_out, int out_size, void* d_ws, size_t ws_size,
                              hipStream_t stream) {
  const int*   x    = (const int*)d_in[0];
  const float* emb  = (const float*)d_in[1];
  const float* Wxh0 = (const float*)d_in[2];
  const float* bxh0 = (const float*)d_in[3];
  const float* Whh0 = (const float*)d_in[4];
  const float* bhh0 = (const float*)d_in[5];
  const float* Wxh1 = (const float*)d_in[6];
  const float* bxh1 = (const float*)d_in[7];
  const float* Whh1 = (const float*)d_in[8];
  const float* bhh1 = (const float*)d_in[9];
  const float* fc_w = (const float*)d_in[10];
  const float* fc_b = (const float*)d_in[11];
  (void)d_ws; (void)ws_size; (void)in_sizes; (void)n_in; (void)out_size;

  const int prep_total = HID * EMBD + 3 * HID * HID;
  hipLaunchKernelGGL(k_init, dim3((NFLAGS + 255) / 256), dim3(256), 0, stream);
  hipLaunchKernelGGL(k_prep, dim3((prep_total + 255) / 256), dim3(256), 0, stream,
                     Wxh0, Whh0, Wxh1, Whh1);
  hipLaunchKernelGGL(k_a, dim3(S_LEN), dim3(256), 0, stream, x, emb, bxh0, bhh0);
  hipLaunchKernelGGL(k_rnn, dim3(64), dim3(512), 0, stream, bxh1, bhh1);
  hipLaunchKernelGGL(k_out, dim3(1), dim3(64), 0, stream,
                     fc_w, fc_b, (float*)d_out);
}